// Round 1
// baseline (466.292 us; speedup 1.0000x reference)
//
#include <hip/hip_runtime.h>
#include <cstdint>
#include <cstddef>

// Problem constants (fixed by the reference).
constexpr int kN = 50000;      // nodes  (< 65536 -> src ids fit in uint16)
constexpr int kE = 800000;     // edges
constexpr int kG = 512;        // graphs
constexpr float kNegSlope = 0.2f;
constexpr float kLog2e = 1.4426950408889634f;

typedef float f4v __attribute__((ext_vector_type(4)));
typedef _Float16 h2v __attribute__((ext_vector_type(2)));
typedef _Float16 h4v __attribute__((ext_vector_type(4)));
typedef _Float16 h8v __attribute__((ext_vector_type(8)));

#if defined(__has_builtin)
#if __has_builtin(__builtin_amdgcn_fdot2)
#define HAS_FDOT2 1
#endif
#endif

__device__ inline float dot2f(h2v a, h2v b, float c) {
#ifdef HAS_FDOT2
  return __builtin_amdgcn_fdot2(a, b, c, false);
#else
  return c + (float)a.x * (float)b.x + (float)a.y * (float)b.y;
#endif
}

// DPP cross-lane add: x + x[lane ^ k] for k representable as a DPP pattern.
// 0xB1 = quad_perm[1,0,3,2] (^1), 0x4E = quad_perm[2,3,0,1] (^2),
// 0x141 = row_half_mirror (^7).  Butterfly with masks {1,2,7} spans the full
// 8-lane group (7^1=6, 7^2=5, 7^1^2=4), so 3 DPP adds == old 3 ds_swizzle
// shfl_xor{1,2,4} — same sum, VALU latency instead of serial LGKM waits.
template <int CTRL>
__device__ inline float dpp_xadd(float x) {
  int s = __builtin_bit_cast(int, x);
  int y = __builtin_amdgcn_update_dpp(s, s, CTRL, 0xF, 0xF, false);
  return x + __builtin_bit_cast(float, y);
}

// ---------------------------------------------------------------------------
// CSR build: histogram of dst (records each edge's within-node slot) ->
// block-scan -> fused top-scan+add -> scatter (no atomics in scatter).
// ---------------------------------------------------------------------------
__global__ void k_hist(const int* __restrict__ dst, int* __restrict__ counts,
                       int* __restrict__ pos, int n) {
  int i = blockIdx.x * blockDim.x + threadIdx.x;
  if (i < n) pos[i] = atomicAdd(&counts[dst[i]], 1);
}

__global__ __launch_bounds__(256) void k_scan_blk(const int* __restrict__ counts,
                                                  int* __restrict__ excl,
                                                  int* __restrict__ bsums, int n) {
  __shared__ int sh[256];
  int tid = threadIdx.x;
  int i = blockIdx.x * 256 + tid;
  int c = (i < n) ? counts[i] : 0;
  sh[tid] = c;
  __syncthreads();
  for (int off = 1; off < 256; off <<= 1) {
    int t = (tid >= off) ? sh[tid - off] : 0;
    __syncthreads();
    sh[tid] += t;
    __syncthreads();
  }
  if (i < n) excl[i] = sh[tid] - c;
  if (tid == 255) bsums[blockIdx.x] = sh[255];
}

__global__ __launch_bounds__(256) void k_scan_add(const int* __restrict__ excl,
                                                  const int* __restrict__ bsums,
                                                  int* __restrict__ row_ptr,
                                                  int n, int nb) {
  __shared__ int sh[256];
  int tid = threadIdx.x;
  int c = (tid < nb) ? bsums[tid] : 0;
  sh[tid] = c;
  __syncthreads();
  for (int off = 1; off < 256; off <<= 1) {
    int t = (tid >= off) ? sh[tid - off] : 0;
    __syncthreads();
    sh[tid] += t;
    __syncthreads();
  }
  int top = (blockIdx.x > 0) ? sh[blockIdx.x - 1] : 0;
  int total = sh[nb - 1];
  __syncthreads();
  int i = blockIdx.x * 256 + tid;
  if (i < n) row_ptr[i] = excl[i] + top;
  if (i == n) row_ptr[n] = total;
}

__global__ void k_scatter(const int* __restrict__ src, const int* __restrict__ dst,
                          const float* __restrict__ eattr,
                          const int* __restrict__ row_ptr, const int* __restrict__ pos,
                          uint16_t* __restrict__ csr_src, _Float16* __restrict__ csr_ea,
                          int n) {
  int i = blockIdx.x * blockDim.x + threadIdx.x;
  if (i >= n) return;
  int p = row_ptr[dst[i]] + pos[i];
  csr_src[p] = (uint16_t)src[i];
  const float4* s4 = (const float4*)eattr + (size_t)i * 2;
  float4 a = s4[0];
  float4 b = s4[1];
  h8v hv;
  hv[0] = (_Float16)a.x; hv[1] = (_Float16)a.y; hv[2] = (_Float16)a.z; hv[3] = (_Float16)a.w;
  hv[4] = (_Float16)b.x; hv[5] = (_Float16)b.y; hv[6] = (_Float16)b.z; hv[7] = (_Float16)b.w;
  *(h8v*)(csr_ea + (size_t)p * 8) = hv;
}

// ---------------------------------------------------------------------------
// Fused prep: zeroes counts, builds graph-boundary table gptr (kills the
// per-block binary search in k_pool_mlp), x -> fp16 padded K=32; weight
// pairs -> fp16 transposed Wt; We -> fp16 transposed Wet[ch][k].
// ---------------------------------------------------------------------------
__global__ __launch_bounds__(256) void k_prep(
    const float* __restrict__ x,
    const float* __restrict__ W1s, const float* __restrict__ W1d,
    const float* __restrict__ W2s, const float* __restrict__ W2d,
    const float* __restrict__ W3s, const float* __restrict__ W3d,
    const float* __restrict__ W1e, const float* __restrict__ W2e,
    const float* __restrict__ W3e,
    const int* __restrict__ batch, int* __restrict__ gptr,
    int* __restrict__ counts,
    _Float16* __restrict__ xf, _Float16* __restrict__ Wt1,
    _Float16* __restrict__ Wt2, _Float16* __restrict__ Wt3,
    _Float16* __restrict__ We1t, _Float16* __restrict__ We2t,
    _Float16* __restrict__ We3t, int n) {
  int i = blockIdx.x * 256 + threadIdx.x;
  if (i < n) {
    counts[i] = 0;
    // gptr[g] = first node of graph g (batch is sorted).  Avg loop len ~0.01.
    int b1 = batch[i];
    int b0 = (i == 0) ? -1 : batch[i - 1];
    for (int g = b0 + 1; g <= b1; ++g) gptr[g] = i;
    if (i == n - 1) {
      for (int g = b1 + 1; g <= kG; ++g) gptr[g] = n;
    }
  }
  i -= n;
  if (i < 0) return;
  int r0 = n * 32;
  if (i < r0) {
    int node = i >> 5, col = i & 31;
    xf[i] = (col < 16) ? (_Float16)x[node * 16 + col] : (_Float16)0.f;
    return;
  }
  i -= r0;
  if (i < 256 * 32) {  // Wt1: 256 cols x K=32, IND=16, OUTD=128
    int c = i >> 5, k = i & 31;
    const float* W = (c < 128) ? W1s : W1d;
    Wt1[i] = (k < 16) ? (_Float16)W[k * 128 + (c & 127)] : (_Float16)0.f;
    return;
  }
  i -= 256 * 32;
  if (i < 256 * 128) {  // Wt2: 256 x 128, IND=128, OUTD=128
    int c = i >> 7, k = i & 127;
    const float* W = (c < 128) ? W2s : W2d;
    Wt2[i] = (_Float16)W[k * 128 + (c & 127)];
    return;
  }
  i -= 256 * 128;
  if (i < 64 * 128) {  // Wt3: 64 x 128, IND=128, OUTD=32
    int c = i >> 7, k = i & 127;
    const float* W = (c < 32) ? W3s : W3d;
    int cc = (c < 32) ? c : c - 32;
    Wt3[i] = (_Float16)W[k * 32 + cc];
    return;
  }
  i -= 64 * 128;
  if (i < 128 * 8) {  // We1t[ch][k] = W1e[k][ch]
    We1t[i] = (_Float16)W1e[(i & 7) * 128 + (i >> 3)];
    return;
  }
  i -= 128 * 8;
  if (i < 128 * 8) {  // We2t
    We2t[i] = (_Float16)W2e[(i & 7) * 128 + (i >> 3)];
    return;
  }
  i -= 128 * 8;
  if (i < 32 * 8) {   // We3t
    We3t[i] = (_Float16)W3e[(i & 7) * 32 + (i >> 3)];
  }
}

// ---------------------------------------------------------------------------
// MFMA node transform: [xs | xd] = h @ [Ws | Wd] + [bs | bd].
// ---------------------------------------------------------------------------
template <int KT, int NC2>
__global__ __launch_bounds__(256) void k_tmfma(
    const _Float16* __restrict__ hf, const _Float16* __restrict__ Wt,
    const float* __restrict__ bs, const float* __restrict__ bd,
    _Float16* __restrict__ xs_h, _Float16* __restrict__ xd_h, int n_nodes) {
  constexpr int K = KT * 32;
  constexpr int NCS = NC2 / 2;
  constexpr int D = NCS * 16;
  int lane = threadIdx.x & 63;
  int wid = threadIdx.x >> 6;
  int m = lane & 15;
  int quad = lane >> 4;
  int base = (blockIdx.x * 4 + wid) * 16;
  if (base >= n_nodes) return;
  int arow = min(base + m, n_nodes - 1);

  h8v a[KT];
#pragma unroll
  for (int t = 0; t < KT; ++t)
    a[t] = *(const h8v*)(hf + (size_t)arow * K + t * 32 + quad * 8);

  bool full = (base + 16 <= n_nodes);
#pragma unroll
  for (int c = 0; c < NC2; ++c) {
    f4v acc = {0.f, 0.f, 0.f, 0.f};
#pragma unroll
    for (int t = 0; t < KT; ++t) {
      h8v b = *(const h8v*)(Wt + (size_t)(c * 16 + m) * K + t * 32 + quad * 8);
      acc = __builtin_amdgcn_mfma_f32_16x16x32_f16(a[t], b, acc, 0, 0, 0);
    }
    float bv = (c < NCS) ? bs[c * 16 + m] : bd[(c - NCS) * 16 + m];
#pragma unroll
    for (int r = 0; r < 4; ++r) {
      int node = base + quad * 4 + r;
      if (full || node < n_nodes) {
        if (c < NCS)
          xs_h[(size_t)node * D + c * 16 + m] = (_Float16)(acc[r] + bv);
        else
          xd_h[(size_t)node * D + (c - NCS) * 16 + m] = (_Float16)(acc[r] + bv);
      }
    }
  }
}

// ---------------------------------------------------------------------------
// Fused GATv2, D=128 (H=4, C=32): NON-persistent, ONE WAVE PER BLOCK,
// TWO NODES PER WAVE sequentially (layer-constant att/we/bias loaded once;
// node1's row_ptr/xd/chunk-0 edges register-prefetched so its startup
// row_ptr->src->gather serial chain hides under node0's compute; node0's
// chunk-0 edge loads issued before the weight loads for the same reason).
// TWO edge slots (32 lanes/slot, 4 ch/lane — measured knee).  Pipeline
// depth 2 with wave-uniform prefetch guard (R12/R15: depth 4 regressed).
// Head-score reduce = 3 DPP adds (masks {1,2,7} butterfly == xor{1,2,4}
// sum over the aligned 8-lane group) — no ds_swizzle in the hot loop.
// Gather addresses pre-scaled into LDS sad[] (broadcast ds_read per slot)
// instead of ds_bpermute; lanes>=cnt stage 0 -> valid address, masked by
// p=0 (index bound <=63 unchanged from the shfl version's proof).
// No-max softmax in log2 domain: att pre-scaled by log2e, p = exp2(sc).
// __launch_bounds__(64,8) pins VGPR<=64 (occupancy halves at 65 — m69).
// ---------------------------------------------------------------------------
template <bool DO_ELU>
__global__ __launch_bounds__(64, 8) void k_gat128(
    const int* __restrict__ row_ptr, const uint16_t* __restrict__ csr_src,
    const _Float16* __restrict__ csr_ea,
    const _Float16* __restrict__ xs_h, const _Float16* __restrict__ xd_h,
    const float* __restrict__ att, const float* __restrict__ bias,
    const _Float16* __restrict__ Wet, _Float16* __restrict__ hout, int n_nodes) {
  __shared__ _Float16 sea[64 * 8];
  __shared__ uint32_t sad[64];
  int lane = threadIdx.x & 63;
  int node0 = blockIdx.x * 2;
  if (node0 >= n_nodes) return;
  int slot = lane >> 5;   // 0 / 1
  int sl = lane & 31;
  int ch0 = sl * 4;       // this lane's 4 channels; head = sl>>3

  // Per-node ranges (block-uniform -> scalar loads).
  int nd1 = min(node0 + 1, n_nodes - 1);
  int beg0 = row_ptr[node0];
  int mid = row_ptr[node0 + 1];
  int end1 = row_ptr[nd1 + 1];

  // Issue node0 chunk-0 edge loads FIRST (overlap with weight loads below).
  int cnt0 = min(mid - beg0, 64);
  int sv0 = 0;
  h8v ea0;
#pragma unroll
  for (int q = 0; q < 8; ++q) ea0[q] = (_Float16)0.f;
  if (cnt0 > 0) {
    int idx = beg0 + ((lane < cnt0) ? lane : 0);  // clamped -> always valid
    sv0 = (int)__builtin_nontemporal_load(csr_src + idx);
    ea0 = __builtin_nontemporal_load((const h8v*)(csr_ea + (size_t)idx * 8));
  }
  // Node1 chunk-0 prefetch (consumed after node0 completes).
  int pcnt = (node0 + 1 < n_nodes) ? min(end1 - mid, 64) : 0;
  int sv1 = 0;
  h8v ea1;
#pragma unroll
  for (int q = 0; q < 8; ++q) ea1[q] = (_Float16)0.f;
  if (pcnt > 0) {
    int idx = mid + ((lane < pcnt) ? lane : 0);
    sv1 = (int)__builtin_nontemporal_load(csr_src + idx);
    ea1 = __builtin_nontemporal_load((const h8v*)(csr_ea + (size_t)idx * 8));
  }

  float4 at4 = *(const float4*)(att + ch0);
  float atl[4] = {at4.x * kLog2e, at4.y * kLog2e, at4.z * kLog2e, at4.w * kLog2e};
  h2v we[4][4];
#pragma unroll
  for (int c = 0; c < 4; ++c) {
    h8v wv = *(const h8v*)(Wet + (size_t)(ch0 + c) * 8);
#pragma unroll
    for (int t = 0; t < 4; ++t) {
      h2v w;
      w[0] = wv[2 * t];
      w[1] = wv[2 * t + 1];
      we[c][t] = w;
    }
  }
  float4 bv4 = *(const float4*)(bias + ch0);
  float bl[4] = {bv4.x, bv4.y, bv4.z, bv4.w};
  h4v xdh0 = *(const h4v*)(xd_h + (size_t)node0 * 128 + ch0);
  h4v xdh1 = *(const h4v*)(xd_h + (size_t)nd1 * 128 + ch0);

  const char* xsb = (const char*)xs_h;
  uint32_t chb = (uint32_t)sl * 8u;  // byte offset of this lane's 4 fp16 ch
  const uint32_t* sp = &sad[slot];

  auto run_node = [&](int node, int beg, int end, h4v xdh, int psv, h8v pea) {
    float xdl[4];
#pragma unroll
    for (int c = 0; c < 4; ++c) xdl[c] = (float)xdh[c];
    float acc[4] = {0.f, 0.f, 0.f, 0.f};
    float l_run = 0.f;
    for (int cbeg = beg; cbeg < end; cbeg += 64) {
      int cnt = min(end - cbeg, 64);
      int sv;
      h8v ev;
      if (cbeg == beg) {       // chunk 0: register-prefetched
        sv = psv;
        ev = pea;
      } else {
        int idx = cbeg + ((lane < cnt) ? lane : 0);
        sv = (int)__builtin_nontemporal_load(csr_src + idx);
        ev = __builtin_nontemporal_load((const h8v*)(csr_ea + (size_t)idx * 8));
      }
      sad[lane] = (lane < cnt) ? ((uint32_t)(uint16_t)sv << 8) : 0u;
      *(h8v*)&sea[lane * 8] = ev;  // lanes>=cnt write dup of edge cbeg: masked

      auto consume = [&](int i, h4v xh) {
        int e = i + slot;          // <= 63 by construction
        const h2v* pe = (const h2v*)&sea[e * 8];
        h2v a0 = pe[0], a1 = pe[1], a2 = pe[2], a3 = pe[3];
        float xf[4];
#pragma unroll
        for (int c = 0; c < 4; ++c) xf[c] = (float)xh[c];
        float sc = 0.f;
#pragma unroll
        for (int c = 0; c < 4; ++c) {
          float z = dot2f(a3, we[c][3],
                    dot2f(a2, we[c][2],
                    dot2f(a1, we[c][1],
                    dot2f(a0, we[c][0], xf[c] + xdl[c]))));
          z = fmaxf(z, kNegSlope * z);
          sc = fmaf(z, atl[c], sc);
        }
        // head score: DPP butterfly over the 8 lanes covering 32 ch
        sc = dpp_xadd<0xB1>(sc);   // ^1
        sc = dpp_xadd<0x4E>(sc);   // ^2
        sc = dpp_xadd<0x141>(sc);  // ^7 (row_half_mirror)
        float p = (e < cnt) ? exp2f(sc) : 0.f;
        l_run += p;
#pragma unroll
        for (int c = 0; c < 4; ++c) acc[c] += p * xf[c];
      };

      uint32_t oa = sp[0] + chb, ob = sp[2] + chb;
      h4v xa = *(const h4v*)(xsb + oa);
      h4v xb = *(const h4v*)(xsb + ob);
      for (int i = 0; i < cnt; i += 4) {
        bool pf = (i + 4 < cnt);   // wave-uniform: zero wasted gathers
        h4v pa, pb;
        if (pf) {
          uint32_t na = sp[i + 4] + chb, nb = sp[i + 6] + chb;
          pa = *(const h4v*)(xsb + na);
          pb = *(const h4v*)(xsb + nb);
        }
        consume(i, xa);
        consume(i + 2, xb);
        if (pf) { xa = pa; xb = pb; }
      }
    }

    // combine the two slots
    l_run += __shfl_xor(l_run, 32, 64);
#pragma unroll
    for (int c = 0; c < 4; ++c) acc[c] += __shfl_xor(acc[c], 32, 64);

    if (slot == 0) {
      float inv = (l_run > 0.f) ? (1.f / l_run) : 0.f;
      h4v ov;
#pragma unroll
      for (int c = 0; c < 4; ++c) {
        float o = acc[c] * inv + bl[c];
        if (DO_ELU) o = (o > 0.f) ? o : (__expf(o) - 1.f);
        ov[c] = (_Float16)o;
      }
      __builtin_nontemporal_store(ov, (h4v*)(hout + (size_t)node * 128 + ch0));
    }
  };

  run_node(node0, beg0, mid, xdh0, sv0, ea0);
  if (node0 + 1 < n_nodes) run_node(node0 + 1, mid, end1, xdh1, sv1, ea1);
}

// ---------------------------------------------------------------------------
// Fused GATv2, D=32 (H=1, C=32): same structure, EIGHT edge slots
// (8 lanes/slot, 4 ch/lane), chunk = 32 edges, 2 nodes/wave, DPP reduce,
// LDS address table, exp2-domain softmax.
// ---------------------------------------------------------------------------
template <bool DO_ELU>
__global__ __launch_bounds__(64, 8) void k_gat32(
    const int* __restrict__ row_ptr, const uint16_t* __restrict__ csr_src,
    const _Float16* __restrict__ csr_ea,
    const _Float16* __restrict__ xs_h, const _Float16* __restrict__ xd_h,
    const float* __restrict__ att, const float* __restrict__ bias,
    const _Float16* __restrict__ Wet, _Float16* __restrict__ hout, int n_nodes) {
  __shared__ _Float16 sea[64 * 8];   // only [0,32*8) read; sized for the
  __shared__ uint32_t sad[64];       // unconditional 64-lane stage
  int lane = threadIdx.x & 63;
  int node0 = blockIdx.x * 2;
  if (node0 >= n_nodes) return;
  int slot = lane >> 3;   // 0..7
  int sl = lane & 7;
  int ch0 = sl * 4;

  int nd1 = min(node0 + 1, n_nodes - 1);
  int beg0 = row_ptr[node0];
  int mid = row_ptr[node0 + 1];
  int end1 = row_ptr[nd1 + 1];

  int cnt0 = min(mid - beg0, 32);
  int sv0 = 0;
  h8v ea0;
#pragma unroll
  for (int q = 0; q < 8; ++q) ea0[q] = (_Float16)0.f;
  if (cnt0 > 0) {
    int idx = beg0 + ((lane < cnt0) ? lane : 0);
    sv0 = (int)__builtin_nontemporal_load(csr_src + idx);
    ea0 = __builtin_nontemporal_load((const h8v*)(csr_ea + (size_t)idx * 8));
  }
  int pcnt = (node0 + 1 < n_nodes) ? min(end1 - mid, 32) : 0;
  int sv1 = 0;
  h8v ea1;
#pragma unroll
  for (int q = 0; q < 8; ++q) ea1[q] = (_Float16)0.f;
  if (pcnt > 0) {
    int idx = mid + ((lane < pcnt) ? lane : 0);
    sv1 = (int)__builtin_nontemporal_load(csr_src + idx);
    ea1 = __builtin_nontemporal_load((const h8v*)(csr_ea + (size_t)idx * 8));
  }

  float4 at4 = *(const float4*)(att + ch0);
  float atl[4] = {at4.x * kLog2e, at4.y * kLog2e, at4.z * kLog2e, at4.w * kLog2e};
  h2v we[4][4];
#pragma unroll
  for (int c = 0; c < 4; ++c) {
    h8v wv = *(const h8v*)(Wet + (size_t)(ch0 + c) * 8);
#pragma unroll
    for (int t = 0; t < 4; ++t) {
      h2v w;
      w[0] = wv[2 * t];
      w[1] = wv[2 * t + 1];
      we[c][t] = w;
    }
  }
  float4 bv4 = *(const float4*)(bias + ch0);
  float bl[4] = {bv4.x, bv4.y, bv4.z, bv4.w};
  h4v xdh0 = *(const h4v*)(xd_h + (size_t)node0 * 32 + ch0);
  h4v xdh1 = *(const h4v*)(xd_h + (size_t)nd1 * 32 + ch0);

  const char* xsb = (const char*)xs_h;
  uint32_t chb = (uint32_t)sl * 8u;
  const uint32_t* sp = &sad[slot];

  auto run_node = [&](int node, int beg, int end, h4v xdh, int psv, h8v pea) {
    float xdl[4];
#pragma unroll
    for (int c = 0; c < 4; ++c) xdl[c] = (float)xdh[c];
    float acc[4] = {0.f, 0.f, 0.f, 0.f};
    float l_run = 0.f;
    for (int cbeg = beg; cbeg < end; cbeg += 32) {
      int cnt = min(end - cbeg, 32);
      int sv;
      h8v ev;
      if (cbeg == beg) {
        sv = psv;
        ev = pea;
      } else {
        int idx = cbeg + ((lane < cnt) ? lane : 0);
        sv = (int)__builtin_nontemporal_load(csr_src + idx);
        ev = __builtin_nontemporal_load((const h8v*)(csr_ea + (size_t)idx * 8));
      }
      sad[lane] = (lane < cnt) ? ((uint32_t)(uint16_t)sv << 6) : 0u;
      *(h8v*)&sea[lane * 8] = ev;

      auto consume = [&](int i, h4v xh) {
        int e = i + slot;          // <= 31 by construction
        const h2v* pe = (const h2v*)&sea[e * 8];
        h2v a0 = pe[0], a1 = pe[1], a2 = pe[2], a3 = pe[3];
        float xf[4];
#pragma unroll
        for (int c = 0; c < 4; ++c) xf[c] = (float)xh[c];
        float sc = 0.f;
#pragma unroll
        for (int c = 0; c < 4; ++c) {
          float z = dot2f(a3, we[c][3],
                    dot2f(a2, we[c][2],
                    dot2f(a1, we[c][1],
                    dot2f(a0, we[c][0], xf[c] + xdl[c]))));
          z = fmaxf(z, kNegSlope * z);
          sc = fmaf(z, atl[c], sc);
        }
        // head = 32 ch = the 8 lanes of this slot (aligned group)
        sc = dpp_xadd<0xB1>(sc);
        sc = dpp_xadd<0x4E>(sc);
        sc = dpp_xadd<0x141>(sc);
        float p = (e < cnt) ? exp2f(sc) : 0.f;
        l_run += p;
#pragma unroll
        for (int c = 0; c < 4; ++c) acc[c] += p * xf[c];
      };

      uint32_t oa = sp[0] + chb, ob = sp[8] + chb;
      h4v xa = *(const h4v*)(xsb + oa);
      h4v xb = *(const h4v*)(xsb + ob);
      for (int i = 0; i < cnt; i += 16) {
        bool pf = (i + 16 < cnt);  // wave-uniform guard
        h4v pa, pb;
        if (pf) {
          uint32_t na = sp[i + 16] + chb, nb = sp[i + 24] + chb;
          pa = *(const h4v*)(xsb + na);
          pb = *(const h4v*)(xsb + nb);
        }
        consume(i, xa);
        consume(i + 8, xb);
        if (pf) { xa = pa; xb = pb; }
      }
    }

    // combine the 8 slots (lanes with equal sl)
#pragma unroll
    for (int off = 8; off < 64; off <<= 1) {
      l_run += __shfl_xor(l_run, off, 64);
#pragma unroll
      for (int c = 0; c < 4; ++c) acc[c] += __shfl_xor(acc[c], off, 64);
    }

    if (slot == 0) {
      float inv = (l_run > 0.f) ? (1.f / l_run) : 0.f;
      h4v ov;
#pragma unroll
      for (int c = 0; c < 4; ++c) {
        float o = acc[c] * inv + bl[c];
        if (DO_ELU) o = (o > 0.f) ? o : (__expf(o) - 1.f);
        ov[c] = (_Float16)o;
      }
      __builtin_nontemporal_store(ov, (h4v*)(hout + (size_t)node * 32 + ch0));
    }
  };

  run_node(node0, beg0, mid, xdh0, sv0, ea0);
  if (node0 + 1 < n_nodes) run_node(node0 + 1, mid, end1, xdh1, sv1, ea1);
}

// ---------------------------------------------------------------------------
// Global mean-pool (fp16 input) + 2-layer MLP.  Graph bounds come from the
// gptr table built in k_prep (replaces 2x16-step dependent-load binsearch).
// ---------------------------------------------------------------------------
__global__ __launch_bounds__(64) void k_pool_mlp(
    const _Float16* __restrict__ h3, const int* __restrict__ gptr,
    const float* __restrict__ Wm1, const float* __restrict__ bm1,
    const float* __restrict__ Wm2, const float* __restrict__ bm2,
    float* __restrict__ out, int n_nodes) {
  int g = blockIdx.x;
  int t = threadIdx.x;
  int lo = gptr[g];
  int hi = gptr[g + 1];
  int c = t & 31, half = t >> 5;
  float sum = 0.f;
  for (int i = lo + half; i < hi; i += 2) sum += (float)h3[(size_t)i * 32 + c];
  sum += __shfl_xor(sum, 32, 64);
  float cnt = (float)(hi - lo);
  float emb = sum / fmaxf(cnt, 1.f);
  __shared__ float sh_emb[32];
  __shared__ float sh_hid[64];
  if (half == 0) sh_emb[c] = emb;
  __syncthreads();
  float hv = bm1[t];
  for (int k = 0; k < 32; ++k) hv += sh_emb[k] * Wm1[k * 64 + t];
  hv = fmaxf(hv, 0.f);
  sh_hid[t] = hv;
  __syncthreads();
  float ov = bm2[t];
  for (int k = 0; k < 64; ++k) ov += sh_hid[k] * Wm2[k * 64 + t];
  out[(size_t)g * 64 + t] = ov;
}

// ---------------------------------------------------------------------------
extern "C" void kernel_launch(void* const* d_in, const int* in_sizes, int n_in,
                              void* d_out, int out_size, void* d_ws, size_t ws_size,
                              hipStream_t stream) {
  const float* x = (const float*)d_in[0];
  const int* esrc = (const int*)d_in[1];
  const int* edst = (const int*)d_in[2];
  const float* eattr = (const float*)d_in[3];
  const int* batch = (const int*)d_in[4];
  const float* W1s = (const float*)d_in[5];
  const float* W1d = (const float*)d_in[6];
  const float* W1e = (const float*)d_in[7];
  const float* b1s = (const float*)d_in[8];
  const float* b1d = (const float*)d_in[9];
  const float* att1 = (const float*)d_in[10];
  const float* bias1 = (const float*)d_in[11];
  const float* W2s = (const float*)d_in[12];
  const float* W2d = (const float*)d_in[13];
  const float* W2e = (const float*)d_in[14];
  const float* b2s = (const float*)d_in[15];
  const float* b2d = (const float*)d_in[16];
  const float* att2 = (const float*)d_in[17];
  const float* bias2 = (const float*)d_in[18];
  const float* W3s = (const float*)d_in[19];
  const float* W3d = (const float*)d_in[20];
  const float* W3e = (const float*)d_in[21];
  const float* b3s = (const float*)d_in[22];
  const float* b3d = (const float*)d_in[23];
  const float* att3 = (const float*)d_in[24];
  const float* bias3 = (const float*)d_in[25];
  const float* Wm1 = (const float*)d_in[26];
  const float* bm1 = (const float*)d_in[27];
  const float* Wm2 = (const float*)d_in[28];
  const float* bm2 = (const float*)d_in[29];

  constexpr int kNB = (kN + 255) / 256;

  char* p = (char*)d_ws;
  auto take = [&](size_t bytes) {
    char* r = p;
    p += (bytes + 255) & ~(size_t)255;
    return r;
  };
  int* row_ptr = (int*)take((size_t)(kN + 1) * sizeof(int));
  int* counts = (int*)take((size_t)kN * sizeof(int));
  int* pos = (int*)take((size_t)kE * sizeof(int));
  int* excl = (int*)take((size_t)kN * sizeof(int));
  int* bsums = (int*)take((size_t)kNB * sizeof(int));
  int* gptr = (int*)take((size_t)(kG + 1) * sizeof(int));
  uint16_t* csr_src = (uint16_t*)take((size_t)kE * sizeof(uint16_t));
  _Float16* csr_ea = (_Float16*)take((size_t)kE * 8 * sizeof(_Float16));
  _Float16* xf = (_Float16*)take((size_t)kN * 32 * sizeof(_Float16));
  _Float16* Wt1 = (_Float16*)take((size_t)256 * 32 * sizeof(_Float16));
  _Float16* Wt2 = (_Float16*)take((size_t)256 * 128 * sizeof(_Float16));
  _Float16* Wt3 = (_Float16*)take((size_t)64 * 128 * sizeof(_Float16));
  _Float16* We1t = (_Float16*)take((size_t)128 * 8 * sizeof(_Float16));
  _Float16* We2t = (_Float16*)take((size_t)128 * 8 * sizeof(_Float16));
  _Float16* We3t = (_Float16*)take((size_t)32 * 8 * sizeof(_Float16));
  _Float16* xs_h = (_Float16*)take((size_t)kN * 128 * sizeof(_Float16));
  _Float16* xd_h = (_Float16*)take((size_t)kN * 128 * sizeof(_Float16));
  _Float16* hA = (_Float16*)take((size_t)kN * 128 * sizeof(_Float16));
  _Float16* hB = (_Float16*)take((size_t)kN * 128 * sizeof(_Float16));
  _Float16* h3 = (_Float16*)take((size_t)kN * 32 * sizeof(_Float16));

  // Prep first (also zeroes counts + builds gptr) -> CSR build -> layers.
  {
    int prep_total = kN + kN * 32 + 256 * 32 + 256 * 128 + 64 * 128 +
                     128 * 8 + 128 * 8 + 32 * 8;
    k_prep<<<(prep_total + 255) / 256, 256, 0, stream>>>(
        x, W1s, W1d, W2s, W2d, W3s, W3d, W1e, W2e, W3e,
        batch, gptr, counts, xf, Wt1, Wt2, Wt3, We1t, We2t, We3t, kN);
  }
  k_hist<<<(kE + 255) / 256, 256, 0, stream>>>(edst, counts, pos, kE);
  k_scan_blk<<<kNB, 256, 0, stream>>>(counts, excl, bsums, kN);
  k_scan_add<<<(kN + 1 + 255) / 256, 256, 0, stream>>>(excl, bsums, row_ptr, kN, kNB);
  k_scatter<<<(kE + 255) / 256, 256, 0, stream>>>(esrc, edst, eattr, row_ptr, pos,
                                                  csr_src, csr_ea, kE);

  constexpr int kTB = (kN + 63) / 64;   // transform blocks (64 nodes each)
  constexpr int kGB = (kN + 1) / 2;     // gat blocks (2 nodes per wave)

  // Layer 1: in=16(pad 32) -> D=128, ELU
  k_tmfma<1, 16><<<kTB, 256, 0, stream>>>(xf, Wt1, b1s, b1d, xs_h, xd_h, kN);
  k_gat128<true><<<kGB, 64, 0, stream>>>(row_ptr, csr_src, csr_ea, xs_h, xd_h,
                                         att1, bias1, We1t, hA, kN);
  // Layer 2: in=128 -> D=128, ELU
  k_tmfma<4, 16><<<kTB, 256, 0, stream>>>(hA, Wt2, b2s, b2d, xs_h, xd_h, kN);
  k_gat128<true><<<kGB, 64, 0, stream>>>(row_ptr, csr_src, csr_ea, xs_h, xd_h,
                                         att2, bias2, We2t, hB, kN);
  // Layer 3: in=128 -> D=32, no ELU
  k_tmfma<4, 4><<<kTB, 256, 0, stream>>>(hB, Wt3, b3s, b3d, xs_h, xd_h, kN);
  k_gat32<false><<<kGB, 64, 0, stream>>>(row_ptr, csr_src, csr_ea, xs_h, xd_h,
                                         att3, bias3, We3t, h3, kN);
  // Pool + MLP
  k_pool_mlp<<<kG, 64, 0, stream>>>(h3, gptr, Wm1, bm1, Wm2, bm2, (float*)d_out, kN);
}

// Round 2
// 429.057 us; speedup vs baseline: 1.0868x; 1.0868x over previous
//
#include <hip/hip_runtime.h>
#include <cstdint>
#include <cstddef>

// Problem constants (fixed by the reference).
constexpr int kN = 50000;      // nodes  (< 65536 -> src ids fit in uint16)
constexpr int kE = 800000;     // edges
constexpr int kG = 512;        // graphs
constexpr float kNegSlope = 0.2f;
constexpr float kLog2e = 1.4426950408889634f;

typedef float f4v __attribute__((ext_vector_type(4)));
typedef _Float16 h2v __attribute__((ext_vector_type(2)));
typedef _Float16 h4v __attribute__((ext_vector_type(4)));
typedef _Float16 h8v __attribute__((ext_vector_type(8)));

#if defined(__has_builtin)
#if __has_builtin(__builtin_amdgcn_fdot2)
#define HAS_FDOT2 1
#endif
#endif

__device__ inline float dot2f(h2v a, h2v b, float c) {
#ifdef HAS_FDOT2
  return __builtin_amdgcn_fdot2(a, b, c, false);
#else
  return c + (float)a.x * (float)b.x + (float)a.y * (float)b.y;
#endif
}

// DPP cross-lane add: x + x[lane ^ k] for k representable as a DPP pattern.
// 0xB1 = quad_perm[1,0,3,2] (^1), 0x4E = quad_perm[2,3,0,1] (^2),
// 0x141 = row_half_mirror (^7).  Butterfly with masks {1,2,7} spans the full
// 8-lane group (subgroup {0..7}), so 3 DPP adds == shfl_xor{1,2,4} sum over
// the aligned 8-lane group — VALU latency instead of serial LGKM waits.
// (Verified correct in R1: passed with identical absmax.)
template <int CTRL>
__device__ inline float dpp_xadd(float x) {
  int s = __builtin_bit_cast(int, x);
  int y = __builtin_amdgcn_update_dpp(s, s, CTRL, 0xF, 0xF, false);
  return x + __builtin_bit_cast(float, y);
}

// ---------------------------------------------------------------------------
// CSR build: histogram of dst (records each edge's within-node slot) ->
// block-scan -> fused top-scan+add -> scatter (no atomics in scatter).
// ---------------------------------------------------------------------------
__global__ void k_hist(const int* __restrict__ dst, int* __restrict__ counts,
                       int* __restrict__ pos, int n) {
  int i = blockIdx.x * blockDim.x + threadIdx.x;
  if (i < n) pos[i] = atomicAdd(&counts[dst[i]], 1);
}

__global__ __launch_bounds__(256) void k_scan_blk(const int* __restrict__ counts,
                                                  int* __restrict__ excl,
                                                  int* __restrict__ bsums, int n) {
  __shared__ int sh[256];
  int tid = threadIdx.x;
  int i = blockIdx.x * 256 + tid;
  int c = (i < n) ? counts[i] : 0;
  sh[tid] = c;
  __syncthreads();
  for (int off = 1; off < 256; off <<= 1) {
    int t = (tid >= off) ? sh[tid - off] : 0;
    __syncthreads();
    sh[tid] += t;
    __syncthreads();
  }
  if (i < n) excl[i] = sh[tid] - c;
  if (tid == 255) bsums[blockIdx.x] = sh[255];
}

__global__ __launch_bounds__(256) void k_scan_add(const int* __restrict__ excl,
                                                  const int* __restrict__ bsums,
                                                  int* __restrict__ row_ptr,
                                                  int n, int nb) {
  __shared__ int sh[256];
  int tid = threadIdx.x;
  int c = (tid < nb) ? bsums[tid] : 0;
  sh[tid] = c;
  __syncthreads();
  for (int off = 1; off < 256; off <<= 1) {
    int t = (tid >= off) ? sh[tid - off] : 0;
    __syncthreads();
    sh[tid] += t;
    __syncthreads();
  }
  int top = (blockIdx.x > 0) ? sh[blockIdx.x - 1] : 0;
  int total = sh[nb - 1];
  __syncthreads();
  int i = blockIdx.x * 256 + tid;
  if (i < n) row_ptr[i] = excl[i] + top;
  if (i == n) row_ptr[n] = total;
}

__global__ void k_scatter(const int* __restrict__ src, const int* __restrict__ dst,
                          const float* __restrict__ eattr,
                          const int* __restrict__ row_ptr, const int* __restrict__ pos,
                          uint16_t* __restrict__ csr_src, _Float16* __restrict__ csr_ea,
                          int n) {
  int i = blockIdx.x * blockDim.x + threadIdx.x;
  if (i >= n) return;
  int p = row_ptr[dst[i]] + pos[i];
  csr_src[p] = (uint16_t)src[i];
  const float4* s4 = (const float4*)eattr + (size_t)i * 2;
  float4 a = s4[0];
  float4 b = s4[1];
  h8v hv;
  hv[0] = (_Float16)a.x; hv[1] = (_Float16)a.y; hv[2] = (_Float16)a.z; hv[3] = (_Float16)a.w;
  hv[4] = (_Float16)b.x; hv[5] = (_Float16)b.y; hv[6] = (_Float16)b.z; hv[7] = (_Float16)b.w;
  *(h8v*)(csr_ea + (size_t)p * 8) = hv;
}

// ---------------------------------------------------------------------------
// Fused prep: zeroes counts, builds graph-boundary table gptr (kills the
// per-block binary search in k_pool_mlp), x -> fp16 padded K=32; weight
// pairs -> fp16 transposed Wt; We -> fp16 transposed Wet[ch][k].
// ---------------------------------------------------------------------------
__global__ __launch_bounds__(256) void k_prep(
    const float* __restrict__ x,
    const float* __restrict__ W1s, const float* __restrict__ W1d,
    const float* __restrict__ W2s, const float* __restrict__ W2d,
    const float* __restrict__ W3s, const float* __restrict__ W3d,
    const float* __restrict__ W1e, const float* __restrict__ W2e,
    const float* __restrict__ W3e,
    const int* __restrict__ batch, int* __restrict__ gptr,
    int* __restrict__ counts,
    _Float16* __restrict__ xf, _Float16* __restrict__ Wt1,
    _Float16* __restrict__ Wt2, _Float16* __restrict__ Wt3,
    _Float16* __restrict__ We1t, _Float16* __restrict__ We2t,
    _Float16* __restrict__ We3t, int n) {
  int i = blockIdx.x * 256 + threadIdx.x;
  if (i < n) {
    counts[i] = 0;
    // gptr[g] = first node of graph g (batch is sorted).  Avg loop len ~0.01.
    int b1 = batch[i];
    int b0 = (i == 0) ? -1 : batch[i - 1];
    for (int g = b0 + 1; g <= b1; ++g) gptr[g] = i;
    if (i == n - 1) {
      for (int g = b1 + 1; g <= kG; ++g) gptr[g] = n;
    }
  }
  i -= n;
  if (i < 0) return;
  int r0 = n * 32;
  if (i < r0) {
    int node = i >> 5, col = i & 31;
    xf[i] = (col < 16) ? (_Float16)x[node * 16 + col] : (_Float16)0.f;
    return;
  }
  i -= r0;
  if (i < 256 * 32) {  // Wt1: 256 cols x K=32, IND=16, OUTD=128
    int c = i >> 5, k = i & 31;
    const float* W = (c < 128) ? W1s : W1d;
    Wt1[i] = (k < 16) ? (_Float16)W[k * 128 + (c & 127)] : (_Float16)0.f;
    return;
  }
  i -= 256 * 32;
  if (i < 256 * 128) {  // Wt2: 256 x 128, IND=128, OUTD=128
    int c = i >> 7, k = i & 127;
    const float* W = (c < 128) ? W2s : W2d;
    Wt2[i] = (_Float16)W[k * 128 + (c & 127)];
    return;
  }
  i -= 256 * 128;
  if (i < 64 * 128) {  // Wt3: 64 x 128, IND=128, OUTD=32
    int c = i >> 7, k = i & 127;
    const float* W = (c < 32) ? W3s : W3d;
    int cc = (c < 32) ? c : c - 32;
    Wt3[i] = (_Float16)W[k * 32 + cc];
    return;
  }
  i -= 64 * 128;
  if (i < 128 * 8) {  // We1t[ch][k] = W1e[k][ch]
    We1t[i] = (_Float16)W1e[(i & 7) * 128 + (i >> 3)];
    return;
  }
  i -= 128 * 8;
  if (i < 128 * 8) {  // We2t
    We2t[i] = (_Float16)W2e[(i & 7) * 128 + (i >> 3)];
    return;
  }
  i -= 128 * 8;
  if (i < 32 * 8) {   // We3t
    We3t[i] = (_Float16)W3e[(i & 7) * 32 + (i >> 3)];
  }
}

// ---------------------------------------------------------------------------
// MFMA node transform: [xs | xd] = h @ [Ws | Wd] + [bs | bd].
// ---------------------------------------------------------------------------
template <int KT, int NC2>
__global__ __launch_bounds__(256) void k_tmfma(
    const _Float16* __restrict__ hf, const _Float16* __restrict__ Wt,
    const float* __restrict__ bs, const float* __restrict__ bd,
    _Float16* __restrict__ xs_h, _Float16* __restrict__ xd_h, int n_nodes) {
  constexpr int K = KT * 32;
  constexpr int NCS = NC2 / 2;
  constexpr int D = NCS * 16;
  int lane = threadIdx.x & 63;
  int wid = threadIdx.x >> 6;
  int m = lane & 15;
  int quad = lane >> 4;
  int base = (blockIdx.x * 4 + wid) * 16;
  if (base >= n_nodes) return;
  int arow = min(base + m, n_nodes - 1);

  h8v a[KT];
#pragma unroll
  for (int t = 0; t < KT; ++t)
    a[t] = *(const h8v*)(hf + (size_t)arow * K + t * 32 + quad * 8);

  bool full = (base + 16 <= n_nodes);
#pragma unroll
  for (int c = 0; c < NC2; ++c) {
    f4v acc = {0.f, 0.f, 0.f, 0.f};
#pragma unroll
    for (int t = 0; t < KT; ++t) {
      h8v b = *(const h8v*)(Wt + (size_t)(c * 16 + m) * K + t * 32 + quad * 8);
      acc = __builtin_amdgcn_mfma_f32_16x16x32_f16(a[t], b, acc, 0, 0, 0);
    }
    float bv = (c < NCS) ? bs[c * 16 + m] : bd[(c - NCS) * 16 + m];
#pragma unroll
    for (int r = 0; r < 4; ++r) {
      int node = base + quad * 4 + r;
      if (full || node < n_nodes) {
        if (c < NCS)
          xs_h[(size_t)node * D + c * 16 + m] = (_Float16)(acc[r] + bv);
        else
          xd_h[(size_t)node * D + (c - NCS) * 16 + m] = (_Float16)(acc[r] + bv);
      }
    }
  }
}

// ---------------------------------------------------------------------------
// Fused GATv2, D=128 (H=4, C=32): NON-persistent, ONE WAVE PER BLOCK,
// ONE NODE PER BLOCK (R1 post-mortem: 2 nodes/wave + register-held cross-
// node prefetch + __launch_bounds__(64,8) spilled to scratch — WRITE_SIZE
// 12.5->94 MB, dur 59->73 µs.  Reverted; structure below is the measured
// optimum).  TWO edge slots (32 lanes/slot, 4 ch/lane — measured knee).
// Pipeline depth 2 with wave-uniform prefetch guard (depth 4 regressed).
// Kept from R1 (all correctness-verified):
//  - head-score reduce = 3 DPP adds (masks {1,2,7} butterfly), no LGKM chain
//  - gather addresses pre-scaled into LDS sad[] (broadcast ds_read per slot)
//    instead of ds_bpermute+shift per gather
//  - no-max softmax in log2 domain: att pre-scaled by log2e, p = exp2(sc)
// No-max is safe: scores bounded ~|6| << 127.
// ---------------------------------------------------------------------------
template <bool DO_ELU>
__global__ __launch_bounds__(64) void k_gat128(
    const int* __restrict__ row_ptr, const uint16_t* __restrict__ csr_src,
    const _Float16* __restrict__ csr_ea,
    const _Float16* __restrict__ xs_h, const _Float16* __restrict__ xd_h,
    const float* __restrict__ att, const float* __restrict__ bias,
    const _Float16* __restrict__ Wet, _Float16* __restrict__ hout, int n_nodes) {
  __shared__ _Float16 sea[64 * 8];
  __shared__ uint32_t sad[64];
  int lane = threadIdx.x & 63;
  int node = blockIdx.x;
  if (node >= n_nodes) return;
  int slot = lane >> 5;   // 0 / 1
  int sl = lane & 31;
  int ch0 = sl * 4;       // this lane's 4 channels; head = sl>>3

  float4 at4 = *(const float4*)(att + ch0);
  float atl[4] = {at4.x * kLog2e, at4.y * kLog2e, at4.z * kLog2e, at4.w * kLog2e};
  h2v we[4][4];
#pragma unroll
  for (int c = 0; c < 4; ++c) {
    h8v wv = *(const h8v*)(Wet + (size_t)(ch0 + c) * 8);
#pragma unroll
    for (int t = 0; t < 4; ++t) {
      h2v w;
      w[0] = wv[2 * t];
      w[1] = wv[2 * t + 1];
      we[c][t] = w;
    }
  }
  float4 bv4 = *(const float4*)(bias + ch0);
  float bl[4] = {bv4.x, bv4.y, bv4.z, bv4.w};

  h4v xdh = *(const h4v*)(xd_h + (size_t)node * 128 + ch0);
  float xdl[4];
#pragma unroll
  for (int c = 0; c < 4; ++c) xdl[c] = (float)xdh[c];

  const char* xsb = (const char*)xs_h;
  uint32_t chb = (uint32_t)sl * 8u;  // byte offset of this lane's 4 fp16 ch
  const uint32_t* sp = &sad[slot];

  float acc[4] = {0.f, 0.f, 0.f, 0.f};
  float l_run = 0.f;
  int beg = row_ptr[node], end = row_ptr[node + 1];

  for (int cbeg = beg; cbeg < end; cbeg += 64) {
    int cnt = min(end - cbeg, 64);
    int sv = (lane < cnt) ? (int)__builtin_nontemporal_load(csr_src + cbeg + lane) : 0;
    sad[lane] = (uint32_t)(uint16_t)sv << 8;  // pre-scaled row byte offset
    if (lane < cnt) {
      h8v t = __builtin_nontemporal_load((const h8v*)(csr_ea + (size_t)(cbeg + lane) * 8));
      *(h8v*)&sea[lane * 8] = t;
    }

    auto consume = [&](int i, h4v xh) {
      int e = i + slot;                  // <= 63 by construction
      const h2v* pe = (const h2v*)&sea[e * 8];
      h2v a0 = pe[0], a1 = pe[1], a2 = pe[2], a3 = pe[3];
      float xf[4];
#pragma unroll
      for (int c = 0; c < 4; ++c) xf[c] = (float)xh[c];
      float sc = 0.f;
#pragma unroll
      for (int c = 0; c < 4; ++c) {
        float z = dot2f(a3, we[c][3],
                  dot2f(a2, we[c][2],
                  dot2f(a1, we[c][1],
                  dot2f(a0, we[c][0], xf[c] + xdl[c]))));
        z = fmaxf(z, kNegSlope * z);
        sc = fmaf(z, atl[c], sc);
      }
      // head score: DPP butterfly over the 8 lanes covering this head's 32 ch
      sc = dpp_xadd<0xB1>(sc);   // ^1
      sc = dpp_xadd<0x4E>(sc);   // ^2
      sc = dpp_xadd<0x141>(sc);  // ^7 (row_half_mirror)
      float p = (e < cnt) ? exp2f(sc) : 0.f;
      l_run += p;
#pragma unroll
      for (int c = 0; c < 4; ++c) acc[c] += p * xf[c];
    };

    uint32_t oa = sp[0] + chb, ob = sp[2] + chb;
    h4v xa = *(const h4v*)(xsb + oa);
    h4v xb = *(const h4v*)(xsb + ob);
    for (int i = 0; i < cnt; i += 4) {
      bool pf = (i + 4 < cnt);           // wave-uniform: zero wasted gathers
      h4v pa, pb;
      if (pf) {
        uint32_t na = sp[i + 4] + chb, nb = sp[i + 6] + chb;
        pa = *(const h4v*)(xsb + na);
        pb = *(const h4v*)(xsb + nb);
      }
      consume(i, xa);
      consume(i + 2, xb);
      if (pf) { xa = pa; xb = pb; }
    }
  }

  // combine the two slots
  l_run += __shfl_xor(l_run, 32, 64);
#pragma unroll
  for (int c = 0; c < 4; ++c) acc[c] += __shfl_xor(acc[c], 32, 64);

  if (slot == 0) {
    float inv = (l_run > 0.f) ? (1.f / l_run) : 0.f;
    h4v ov;
#pragma unroll
    for (int c = 0; c < 4; ++c) {
      float o = acc[c] * inv + bl[c];
      if (DO_ELU) o = (o > 0.f) ? o : (__expf(o) - 1.f);
      ov[c] = (_Float16)o;
    }
    __builtin_nontemporal_store(ov, (h4v*)(hout + (size_t)node * 128 + ch0));
  }
}

// ---------------------------------------------------------------------------
// Fused GATv2, D=32 (H=1, C=32): one node per block, EIGHT edge slots
// (8 lanes/slot, 4 ch/lane), chunk = 32 edges, pipeline depth 2 with
// wave-uniform guard, DPP reduce, LDS address table, exp2-domain softmax.
// ---------------------------------------------------------------------------
template <bool DO_ELU>
__global__ __launch_bounds__(64) void k_gat32(
    const int* __restrict__ row_ptr, const uint16_t* __restrict__ csr_src,
    const _Float16* __restrict__ csr_ea,
    const _Float16* __restrict__ xs_h, const _Float16* __restrict__ xd_h,
    const float* __restrict__ att, const float* __restrict__ bias,
    const _Float16* __restrict__ Wet, _Float16* __restrict__ hout, int n_nodes) {
  __shared__ _Float16 sea[32 * 8];
  __shared__ uint32_t sad[64];
  int lane = threadIdx.x & 63;
  int node = blockIdx.x;
  if (node >= n_nodes) return;
  int slot = lane >> 3;   // 0..7
  int sl = lane & 7;
  int ch0 = sl * 4;

  float4 at4 = *(const float4*)(att + ch0);
  float atl[4] = {at4.x * kLog2e, at4.y * kLog2e, at4.z * kLog2e, at4.w * kLog2e};
  h2v we[4][4];
#pragma unroll
  for (int c = 0; c < 4; ++c) {
    h8v wv = *(const h8v*)(Wet + (size_t)(ch0 + c) * 8);
#pragma unroll
    for (int t = 0; t < 4; ++t) {
      h2v w;
      w[0] = wv[2 * t];
      w[1] = wv[2 * t + 1];
      we[c][t] = w;
    }
  }
  float4 bv4 = *(const float4*)(bias + ch0);
  float bl[4] = {bv4.x, bv4.y, bv4.z, bv4.w};

  h4v xdh = *(const h4v*)(xd_h + (size_t)node * 32 + ch0);
  float xdl[4];
#pragma unroll
  for (int c = 0; c < 4; ++c) xdl[c] = (float)xdh[c];

  const char* xsb = (const char*)xs_h;
  uint32_t chb = (uint32_t)sl * 8u;
  const uint32_t* sp = &sad[slot];

  float acc[4] = {0.f, 0.f, 0.f, 0.f};
  float l_run = 0.f;
  int beg = row_ptr[node], end = row_ptr[node + 1];

  for (int cbeg = beg; cbeg < end; cbeg += 32) {
    int cnt = min(end - cbeg, 32);
    int sv = (lane < cnt) ? (int)__builtin_nontemporal_load(csr_src + cbeg + lane) : 0;
    if (lane < 32) sad[lane] = (uint32_t)(uint16_t)sv << 6;  // row stride 64 B
    if (lane < cnt) {
      h8v t = __builtin_nontemporal_load((const h8v*)(csr_ea + (size_t)(cbeg + lane) * 8));
      *(h8v*)&sea[lane * 8] = t;
    }

    auto consume = [&](int i, h4v xh) {
      int e = i + slot;                  // <= 31 by construction
      const h2v* pe = (const h2v*)&sea[e * 8];
      h2v a0 = pe[0], a1 = pe[1], a2 = pe[2], a3 = pe[3];
      float xf[4];
#pragma unroll
      for (int c = 0; c < 4; ++c) xf[c] = (float)xh[c];
      float sc = 0.f;
#pragma unroll
      for (int c = 0; c < 4; ++c) {
        float z = dot2f(a3, we[c][3],
                  dot2f(a2, we[c][2],
                  dot2f(a1, we[c][1],
                  dot2f(a0, we[c][0], xf[c] + xdl[c]))));
        z = fmaxf(z, kNegSlope * z);
        sc = fmaf(z, atl[c], sc);
      }
      // head = 32 ch = the 8 lanes of this slot (aligned group)
      sc = dpp_xadd<0xB1>(sc);
      sc = dpp_xadd<0x4E>(sc);
      sc = dpp_xadd<0x141>(sc);
      float p = (e < cnt) ? exp2f(sc) : 0.f;
      l_run += p;
#pragma unroll
      for (int c = 0; c < 4; ++c) acc[c] += p * xf[c];
    };

    uint32_t oa = sp[0] + chb, ob = sp[8] + chb;
    h4v xa = *(const h4v*)(xsb + oa);
    h4v xb = *(const h4v*)(xsb + ob);
    for (int i = 0; i < cnt; i += 16) {
      bool pf = (i + 16 < cnt);          // wave-uniform guard
      h4v pa, pb;
      if (pf) {
        uint32_t na = sp[i + 16] + chb, nb = sp[i + 24] + chb;
        pa = *(const h4v*)(xsb + na);
        pb = *(const h4v*)(xsb + nb);
      }
      consume(i, xa);
      consume(i + 8, xb);
      if (pf) { xa = pa; xb = pb; }
    }
  }

  // combine the 8 slots (lanes with equal sl)
#pragma unroll
  for (int off = 8; off < 64; off <<= 1) {
    l_run += __shfl_xor(l_run, off, 64);
#pragma unroll
    for (int c = 0; c < 4; ++c) acc[c] += __shfl_xor(acc[c], off, 64);
  }

  if (slot == 0) {
    float inv = (l_run > 0.f) ? (1.f / l_run) : 0.f;
    h4v ov;
#pragma unroll
    for (int c = 0; c < 4; ++c) {
      float o = acc[c] * inv + bl[c];
      if (DO_ELU) o = (o > 0.f) ? o : (__expf(o) - 1.f);
      ov[c] = (_Float16)o;
    }
    __builtin_nontemporal_store(ov, (h4v*)(hout + (size_t)node * 32 + ch0));
  }
}

// ---------------------------------------------------------------------------
// Global mean-pool (fp16 input) + 2-layer MLP.  Graph bounds come from the
// gptr table built in k_prep (replaces 2x16-step dependent-load binsearch).
// ---------------------------------------------------------------------------
__global__ __launch_bounds__(64) void k_pool_mlp(
    const _Float16* __restrict__ h3, const int* __restrict__ gptr,
    const float* __restrict__ Wm1, const float* __restrict__ bm1,
    const float* __restrict__ Wm2, const float* __restrict__ bm2,
    float* __restrict__ out, int n_nodes) {
  int g = blockIdx.x;
  int t = threadIdx.x;
  int lo = gptr[g];
  int hi = gptr[g + 1];
  int c = t & 31, half = t >> 5;
  float sum = 0.f;
  for (int i = lo + half; i < hi; i += 2) sum += (float)h3[(size_t)i * 32 + c];
  sum += __shfl_xor(sum, 32, 64);
  float cnt = (float)(hi - lo);
  float emb = sum / fmaxf(cnt, 1.f);
  __shared__ float sh_emb[32];
  __shared__ float sh_hid[64];
  if (half == 0) sh_emb[c] = emb;
  __syncthreads();
  float hv = bm1[t];
  for (int k = 0; k < 32; ++k) hv += sh_emb[k] * Wm1[k * 64 + t];
  hv = fmaxf(hv, 0.f);
  sh_hid[t] = hv;
  __syncthreads();
  float ov = bm2[t];
  for (int k = 0; k < 64; ++k) ov += sh_hid[k] * Wm2[k * 64 + t];
  out[(size_t)g * 64 + t] = ov;
}

// ---------------------------------------------------------------------------
extern "C" void kernel_launch(void* const* d_in, const int* in_sizes, int n_in,
                              void* d_out, int out_size, void* d_ws, size_t ws_size,
                              hipStream_t stream) {
  const float* x = (const float*)d_in[0];
  const int* esrc = (const int*)d_in[1];
  const int* edst = (const int*)d_in[2];
  const float* eattr = (const float*)d_in[3];
  const int* batch = (const int*)d_in[4];
  const float* W1s = (const float*)d_in[5];
  const float* W1d = (const float*)d_in[6];
  const float* W1e = (const float*)d_in[7];
  const float* b1s = (const float*)d_in[8];
  const float* b1d = (const float*)d_in[9];
  const float* att1 = (const float*)d_in[10];
  const float* bias1 = (const float*)d_in[11];
  const float* W2s = (const float*)d_in[12];
  const float* W2d = (const float*)d_in[13];
  const float* W2e = (const float*)d_in[14];
  const float* b2s = (const float*)d_in[15];
  const float* b2d = (const float*)d_in[16];
  const float* att2 = (const float*)d_in[17];
  const float* bias2 = (const float*)d_in[18];
  const float* W3s = (const float*)d_in[19];
  const float* W3d = (const float*)d_in[20];
  const float* W3e = (const float*)d_in[21];
  const float* b3s = (const float*)d_in[22];
  const float* b3d = (const float*)d_in[23];
  const float* att3 = (const float*)d_in[24];
  const float* bias3 = (const float*)d_in[25];
  const float* Wm1 = (const float*)d_in[26];
  const float* bm1 = (const float*)d_in[27];
  const float* Wm2 = (const float*)d_in[28];
  const float* bm2 = (const float*)d_in[29];

  constexpr int kNB = (kN + 255) / 256;

  char* p = (char*)d_ws;
  auto take = [&](size_t bytes) {
    char* r = p;
    p += (bytes + 255) & ~(size_t)255;
    return r;
  };
  int* row_ptr = (int*)take((size_t)(kN + 1) * sizeof(int));
  int* counts = (int*)take((size_t)kN * sizeof(int));
  int* pos = (int*)take((size_t)kE * sizeof(int));
  int* excl = (int*)take((size_t)kN * sizeof(int));
  int* bsums = (int*)take((size_t)kNB * sizeof(int));
  int* gptr = (int*)take((size_t)(kG + 1) * sizeof(int));
  uint16_t* csr_src = (uint16_t*)take((size_t)kE * sizeof(uint16_t));
  _Float16* csr_ea = (_Float16*)take((size_t)kE * 8 * sizeof(_Float16));
  _Float16* xf = (_Float16*)take((size_t)kN * 32 * sizeof(_Float16));
  _Float16* Wt1 = (_Float16*)take((size_t)256 * 32 * sizeof(_Float16));
  _Float16* Wt2 = (_Float16*)take((size_t)256 * 128 * sizeof(_Float16));
  _Float16* Wt3 = (_Float16*)take((size_t)64 * 128 * sizeof(_Float16));
  _Float16* We1t = (_Float16*)take((size_t)128 * 8 * sizeof(_Float16));
  _Float16* We2t = (_Float16*)take((size_t)128 * 8 * sizeof(_Float16));
  _Float16* We3t = (_Float16*)take((size_t)32 * 8 * sizeof(_Float16));
  _Float16* xs_h = (_Float16*)take((size_t)kN * 128 * sizeof(_Float16));
  _Float16* xd_h = (_Float16*)take((size_t)kN * 128 * sizeof(_Float16));
  _Float16* hA = (_Float16*)take((size_t)kN * 128 * sizeof(_Float16));
  _Float16* hB = (_Float16*)take((size_t)kN * 128 * sizeof(_Float16));
  _Float16* h3 = (_Float16*)take((size_t)kN * 32 * sizeof(_Float16));

  // Prep first (also zeroes counts + builds gptr) -> CSR build -> layers.
  {
    int prep_total = kN + kN * 32 + 256 * 32 + 256 * 128 + 64 * 128 +
                     128 * 8 + 128 * 8 + 32 * 8;
    k_prep<<<(prep_total + 255) / 256, 256, 0, stream>>>(
        x, W1s, W1d, W2s, W2d, W3s, W3d, W1e, W2e, W3e,
        batch, gptr, counts, xf, Wt1, Wt2, Wt3, We1t, We2t, We3t, kN);
  }
  k_hist<<<(kE + 255) / 256, 256, 0, stream>>>(edst, counts, pos, kE);
  k_scan_blk<<<kNB, 256, 0, stream>>>(counts, excl, bsums, kN);
  k_scan_add<<<(kN + 1 + 255) / 256, 256, 0, stream>>>(excl, bsums, row_ptr, kN, kNB);
  k_scatter<<<(kE + 255) / 256, 256, 0, stream>>>(esrc, edst, eattr, row_ptr, pos,
                                                  csr_src, csr_ea, kE);

  constexpr int kTB = (kN + 63) / 64;   // transform blocks (64 nodes each)

  // Layer 1: in=16(pad 32) -> D=128, ELU
  k_tmfma<1, 16><<<kTB, 256, 0, stream>>>(xf, Wt1, b1s, b1d, xs_h, xd_h, kN);
  k_gat128<true><<<kN, 64, 0, stream>>>(row_ptr, csr_src, csr_ea, xs_h, xd_h,
                                        att1, bias1, We1t, hA, kN);
  // Layer 2: in=128 -> D=128, ELU
  k_tmfma<4, 16><<<kTB, 256, 0, stream>>>(hA, Wt2, b2s, b2d, xs_h, xd_h, kN);
  k_gat128<true><<<kN, 64, 0, stream>>>(row_ptr, csr_src, csr_ea, xs_h, xd_h,
                                        att2, bias2, We2t, hB, kN);
  // Layer 3: in=128 -> D=32, no ELU
  k_tmfma<4, 4><<<kTB, 256, 0, stream>>>(hB, Wt3, b3s, b3d, xs_h, xd_h, kN);
  k_gat32<false><<<kN, 64, 0, stream>>>(row_ptr, csr_src, csr_ea, xs_h, xd_h,
                                        att3, bias3, We3t, h3, kN);
  // Pool + MLP
  k_pool_mlp<<<kG, 64, 0, stream>>>(h3, gptr, Wm1, bm1, Wm2, bm2, (float*)d_out, kN);
}